// Round 5
// baseline (321.113 us; speedup 1.0000x reference)
//
#include <hip/hip_runtime.h>
#include <hip/hip_cooperative_groups.h>

namespace cg = cooperative_groups;

#define NB 8
#define C 256
#define HW 52
#define P (HW*HW)            // 2704
#define NTOPK 4
#define SCALE 0.0625f

// exact unsigned div helpers (verified ranges)
static __device__ __forceinline__ int d7(int v)  { return (v*9363) >> 16; }   // v <= 3135
static __device__ __forceinline__ int d56(int v) { return (v*18725) >> 20; }  // v <= 3135
static __device__ __forceinline__ int d13(int v) { return (v*10083) >> 17; }  // v <= 675

// scratch offsets (floats) in out for the mega kernel
#define OFF_XR 0
#define OFF_YR 131072
#define OFF_XG 262144
#define OFF_G  786432
#define OFF_GR 1310720
#define OFF_M  1441792
#define OFF_U  1507328
#define OFF_V2 1507584
#define OFF_C0 1507840
#define OFF_YT 1507856          // + 8*2704*256 = ends 7,045,648 floats (28.2 MB)

// =============================================================================
// MEGA cooperative kernel: 512 blocks x 256 threads, 2 blocks/CU (LDS 56.1 KB)
// Phase1: prep(M,u,v2,c0) + pool(xr,yr,xg) + y-transpose(yT)
// Phase2: G = xg^T M + u  and  Gr = xr^T M + u   (GEMM, 160 units)
// Phase3: a_r row + top-4 + vals   (1 unit per block)
// Phase4: fill out (21632 units)
// =============================================================================
__global__ __launch_bounds__(256, 2) void mega(
    const float* __restrict__ x, const float* __restrict__ y,
    const float* __restrict__ qw, const float* __restrict__ qb,
    const float* __restrict__ kw, const float* __restrict__ kb,
    float* __restrict__ out, float* __restrict__ ws)
{
    cg::grid_group grid = cg::this_grid();
    __shared__ float sm[14032];         // 56128 B
    const int tid = threadIdx.x;
    const int bid = blockIdx.x;
    const int w = tid >> 6, lane = tid & 63;

    float* xr = out + OFF_XR;
    float* yr = out + OFF_YR;
    float* xg = out + OFF_XG;
    float* G  = out + OFF_G;
    float* Gr = out + OFF_GR;
    float* M  = out + OFF_M;
    float* uu = out + OFF_U;
    float* v2 = out + OFF_V2;
    float* c0 = out + OFF_C0;
    float* yT = out + OFF_YT;
    float* arT = ws;                    // 8*64*64
    float* vls = ws + 32768;            // 8*64*4*49
    int*   idx = (int*)(ws + 133120);   // 8*64*4

    // ================= Phase 1: units 0..64 prep | 65..1088 pool | 1089..2464 transpose
    for (int un = bid; un < 2465; un += 512) {
        __syncthreads();
        if (un < 65) {
            const int pb = un;
            if (pb == 64) {
                float ua = 0.f, va = 0.f;
                for (int e = 0; e < 256; e++) {
                    ua += qb[e] * kw[e*256 + tid];
                    va += kb[e] * qw[e*256 + tid];
                }
                uu[tid] = ua; v2[tid] = va;
                if (tid == 0) {
                    float cc = 0.f;
                    for (int e = 0; e < 256; e++) cc += qb[e]*kb[e];
                    c0[0] = cc;
                }
            } else {
                const int cx0 = pb * 4;
                float (*wqs)[4] = (float(*)[4])sm;
                *(float4*)&wqs[tid][0] = *(const float4*)(qw + tid*256 + cx0);
                __syncthreads();
                float a0=0.f, a1=0.f, a2=0.f, a3=0.f;
                #pragma unroll 4
                for (int o = 0; o < 256; o++) {
                    const float wk = kw[o*256 + tid];
                    const float4 wq = *(const float4*)&wqs[o][0];
                    a0 += wq.x*wk; a1 += wq.y*wk; a2 += wq.z*wk; a3 += wq.w*wk;
                }
                M[(cx0+0)*256 + tid] = a0;
                M[(cx0+1)*256 + tid] = a1;
                M[(cx0+2)*256 + tid] = a2;
                M[(cx0+3)*256 + tid] = a3;
            }
        } else if (un < 1089) {
            // pool: wave w handles plane (un-65)*4+w
            const int pl = (un - 65)*4 + w;
            const int proj = pl >> 11;
            const int bcid = pl & 2047;
            const float* src = (proj ? y : x) + (size_t)bcid * P;
            float* plane = sm + w*P;
            {
                const float4* s4 = (const float4*)src;
                float4* p4 = (float4*)plane;
                for (int g = lane; g < 676; g += 64) p4[g] = s4[g];
            }
            __syncthreads();
            const int jh = lane >> 3, jw = lane & 7;
            const int y0 = jh*7, x0 = jw*7;
            const int ry = min(7, HW - y0), rx = min(7, HW - x0);
            float s = 0.f;
            for (int dy = 0; dy < ry; ++dy) {
                const float* row = plane + (y0 + dy)*HW + x0;
                for (int dx = 0; dx < rx; ++dx) s += row[dx];
            }
            (proj ? yr : xr)[bcid*64 + lane] = s / (float)(ry*rx);
            if (!proj) {
                const float* r0 = plane + y0*HW + x0;
                float4 g4;
                g4.x = r0[0]; g4.y = r0[1]; g4.z = r0[2];
                g4.w = (x0 + 3 < HW) ? r0[3] : 0.f;
                *(float4*)&xg[bcid*256 + lane*4] = g4;
            }
        } else {
            // transpose 64c x 64pos tile of y into yT[b][pos][c]
            const int tb = un - 1089;
            const int b = tb / 172;
            const int rem = tb - b*172;
            const int ct = rem / 43;
            const int pt = rem - ct*43;
            const int cc0 = ct*64, pos0 = pt*64;
            float* tile = sm;               // [64][65]
            const float* ysrc = y + ((size_t)(b*256 + cc0))*P;
            #pragma unroll
            for (int p = 0; p < 4; p++) {
                const int cr = p*16 + (tid>>4);
                const int f4 = tid&15;
                const int pos = pos0 + f4*4;
                if (pos < P) {
                    const float4 v = *(const float4*)(ysrc + (size_t)cr*P + pos);
                    float* d = tile + cr*65 + f4*4;
                    d[0]=v.x; d[1]=v.y; d[2]=v.z; d[3]=v.w;
                }
            }
            __syncthreads();
            #pragma unroll
            for (int p = 0; p < 4; p++) {
                const int pj = p*16 + (tid>>4);
                const int c4 = tid&15;
                const int pos = pos0 + pj;
                if (pos < P) {
                    float4 v;
                    v.x = tile[(c4*4+0)*65 + pj];
                    v.y = tile[(c4*4+1)*65 + pj];
                    v.z = tile[(c4*4+2)*65 + pj];
                    v.w = tile[(c4*4+3)*65 + pj];
                    *(float4*)(yT + ((size_t)(b*P + pos))*256 + cc0 + c4*4) = v;
                }
            }
        }
    }
    grid.sync();

    // ================= Phase 2: 160 GEMM units: b(8) x ptile(5) x otile(4)
    for (int un = bid; un < 160; un += 512) {
        const int b = un / 20;
        const int rem = un - b*20;
        const int pt = rem >> 2, ot = rem & 3;
        const int o0 = ot*64;
        float* As = sm;            // [32][64]
        float* Bs = sm + 2048;     // [32][64]
        const int tx = tid & 15, ty = tid >> 4;
        float acc[4][4];
        #pragma unroll
        for (int i = 0; i < 4; i++)
            #pragma unroll
            for (int j = 0; j < 4; j++) acc[i][j] = 0.f;

        const int lkr = tid >> 3;
        const int ljc = (tid & 7) * 8;
        const float* Asrc; int astr;
        if (pt < 4) { Asrc = xg + (size_t)b*C*256 + pt*64; astr = 256; }
        else        { Asrc = xr + (size_t)b*C*64;          astr = 64;  }

        for (int k0 = 0; k0 < 256; k0 += 32) {
            const float4 a0 = *(const float4*)(Asrc + (k0 + lkr)*astr + ljc);
            const float4 a1 = *(const float4*)(Asrc + (k0 + lkr)*astr + ljc + 4);
            const float4 b0 = *(const float4*)(M + (k0 + lkr)*256 + o0 + ljc);
            const float4 b1 = *(const float4*)(M + (k0 + lkr)*256 + o0 + ljc + 4);
            __syncthreads();
            *(float4*)&As[lkr*64 + ljc] = a0; *(float4*)&As[lkr*64 + ljc + 4] = a1;
            *(float4*)&Bs[lkr*64 + ljc] = b0; *(float4*)&Bs[lkr*64 + ljc + 4] = b1;
            __syncthreads();
            #pragma unroll
            for (int kk = 0; kk < 32; kk++) {
                const float4 a = *(const float4*)&As[kk*64 + ty*4];
                const float4 bb = *(const float4*)&Bs[kk*64 + tx*4];
                const float av[4] = {a.x, a.y, a.z, a.w};
                const float bv[4] = {bb.x, bb.y, bb.z, bb.w};
                #pragma unroll
                for (int i = 0; i < 4; i++)
                    #pragma unroll
                    for (int j = 0; j < 4; j++) acc[i][j] += av[i]*bv[j];
            }
        }
        const float4 u4 = *(const float4*)(uu + o0 + tx*4);
        float* base = (pt < 4) ? (G + ((size_t)b*256 + pt*64)*256)
                               : (Gr + (size_t)b*64*256);
        #pragma unroll
        for (int i = 0; i < 4; i++) {
            float4 ov;
            ov.x = acc[i][0]+u4.x; ov.y = acc[i][1]+u4.y;
            ov.z = acc[i][2]+u4.z; ov.w = acc[i][3]+u4.w;
            *(float4*)(base + (ty*4 + i)*256 + o0 + tx*4) = ov;
        }
        __syncthreads();
    }
    grid.sync();

    // ================= Phase 3: one (b,r) per block
    {
        const int b = bid >> 6, r = bid & 63;
        float* Ys   = sm;            // [49][260]
        float* Gs   = sm + 12740;    // [4][256]
        float* pdot = sm + 13764;    // [4][64]
        float* aux  = sm + 14020;    // [0..3]=H, [4..7]=ci parts, [8]=gsh(int)

        // A: dot_j partials (Gr row . yr cols) + ci partials
        {
            const float* GrRow = Gr + ((size_t)b*64 + r)*256;
            const float* yrB = yr + b*C*64;
            const float* xrB = xr + b*C*64;
            float d = 0.f, av = 0.f;
            #pragma unroll 8
            for (int cc = 0; cc < 64; cc++) {
                const int c = w*64 + cc;
                const float g = GrRow[c];
                d += g * yrB[c*64 + lane];
                av += v2[c] * xrB[c*64 + r];
            }
            pdot[w*64 + lane] = d;
            if (lane == 0) aux[4 + w] = av;
        }
        // G rows for vals
        *(float4*)&Gs[w*256 + lane*4] =
            *(const float4*)(G + ((size_t)(b*256 + r*4 + w))*256 + lane*4);
        // H[w] = xg[.,r*4+w] . v2 + c0
        {
            const int pos = r*4 + w;
            float acc = 0.f;
            #pragma unroll
            for (int cc = 0; cc < 4; cc++) {
                const int c = lane + cc*64;
                acc += xg[((size_t)(b*256 + c))*256 + pos] * v2[c];
            }
            #pragma unroll
            for (int off = 32; off >= 1; off >>= 1) acc += __shfl_xor(acc, off);
            if (lane == 0) aux[w] = acc + c0[0];
        }
        __syncthreads();

        // B: warp0 — full dot, arT, top-4 (low-index tie-break)
        if (w == 0) {
            const float ci = aux[4] + aux[5] + aux[6] + aux[7] + c0[0];
            const float dot = pdot[lane] + pdot[64+lane] + pdot[128+lane]
                            + pdot[192+lane] + ci;
            arT[(b*64 + lane)*64 + r] = dot * SCALE;
            float v = dot;
            const int my = lane;
            #pragma unroll
            for (int t = 0; t < NTOPK; t++) {
                float bv = v; int bi = my;
                #pragma unroll
                for (int off = 32; off >= 1; off >>= 1) {
                    const float ov = __shfl_xor(bv, off);
                    const int   oi = __shfl_xor(bi, off);
                    if (ov > bv || (ov == bv && oi < bi)) { bv = ov; bi = oi; }
                }
                if (lane == 0) {
                    idx[(b*64 + r)*NTOPK + t] = bi;
                    if (t == NTOPK-1) ((int*)aux)[8] = bi;
                }
                if (my == bi) v = -3.0e38f;
            }
        }
        __syncthreads();

        // C: stage yT rows for region g
        const int g = ((int*)aux)[8];
        const int gy = g >> 3, gx = g & 7;
        for (int i = tid; i < 49*64; i += 256) {
            const int k2 = i >> 6, f4 = i & 63;
            const int dy = d7(k2), dx = k2 - dy*7;
            const int kY = gy*7 + dy, kX = gx*7 + dx;
            float4 v = make_float4(0.f, 0.f, 0.f, 0.f);
            if (kY < HW && kX < HW)
                v = *(const float4*)(yT + ((size_t)(b*P + kY*HW + kX))*256 + f4*4);
            *(float4*)&Ys[k2*260 + f4*4] = v;
        }
        __syncthreads();

        // E: vals
        if (tid < NTOPK*49) {
            const int t = tid / 49, k2 = tid - (tid/49)*49;
            const int qX = (r & 7)*7 + t;
            const int dy = d7(k2), dx = k2 - dy*7;
            const int kY = gy*7 + dy, kX = gx*7 + dx;
            float res = 0.f;
            if (qX < HW && kY < HW && kX < HW) {
                const float4* Gp = (const float4*)&Gs[t*256];
                const float4* Yp = (const float4*)&Ys[k2*260];
                float dot = 0.f;
                #pragma unroll 8
                for (int cc = 0; cc < 64; cc++) {
                    const float4 a = Gp[cc], yy = Yp[cc];
                    dot += a.x*yy.x + a.y*yy.y + a.z*yy.z + a.w*yy.w;
                }
                res = SCALE * (dot + aux[t]);
            }
            vls[((b*64 + r)*NTOPK + t)*49 + k2] = res;
        }
    }
    grid.sync();

    // ================= Phase 4: fill out — 21632 units
    {
        float* acol = sm;        // 64
        float* vrow = sm + 64;   // 49
        for (int un = bid; un < NB*P; un += 512) {
            __syncthreads();
            const int b = un / P;
            const int yx = un - b*P;
            const int Y1 = yx / HW, X1 = yx - (yx/HW)*HW;
            const int r1 = (Y1/7)*8 + X1/7;
            const int q1 = (Y1%7)*7 + X1%7;
            const int p2 = r1*49 + q1;
            const int yy = p2/56, xx = p2 - 56*yy;
            const int regB = (yy/7)*8 + xx/7;

            if (tid < 64) acol[tid] = arT[(b*64 + regB)*64 + tid];
            int ovr = -1;
            if (q1 < NTOPK) {
                ovr = idx[(b*64 + r1)*NTOPK + q1];
                if (tid < 49) vrow[tid] = vls[((b*64 + r1)*NTOPK + q1)*49 + tid];
            }
            __syncthreads();

            float* plane = out + (size_t)(b*P + yx) * P;
            for (int u = tid; u < 676; u += 256) {
                const int Y2 = d13(u);
                const int g4 = u - Y2*13;
                const int X2b = g4*4;
                const int ry2 = d7(Y2);
                const int my2 = Y2 - ry2*7;
                float res[4];
                #pragma unroll
                for (int j = 0; j < 4; j++) {
                    const int X2 = X2b + j;
                    const int rx2 = d7(X2);
                    const int mx2 = X2 - rx2*7;
                    const int r2 = ry2*8 + rx2;
                    const int k2 = my2*7 + mx2;
                    const int P1 = r2*49 + k2;
                    const int Yp = d56(P1);
                    const int Xp = P1 - Yp*56;
                    const int regA = d7(Yp)*8 + d7(Xp);
                    float v = acol[regA];
                    if (r2 == ovr) v = vrow[k2];
                    res[j] = v;
                }
                float4 o; o.x = res[0]; o.y = res[1]; o.z = res[2]; o.w = res[3];
                *(float4*)(plane + Y2*HW + X2b) = o;
            }
        }
    }
}

// =============================================================================
// Fallback: proven R4 4-kernel pipeline (used only if cooperative launch fails)
// =============================================================================
__global__ __launch_bounds__(256) void k1_pool_prep_tr(
    const float* __restrict__ x, const float* __restrict__ y,
    const float* __restrict__ qw, const float* __restrict__ qb,
    const float* __restrict__ kw, const float* __restrict__ kb,
    float* __restrict__ xr, float* __restrict__ yr, float* __restrict__ xg,
    float* __restrict__ M, float* __restrict__ u, float* __restrict__ v2,
    float* __restrict__ c0p, float* __restrict__ yT)
{
    __shared__ float sm[4*P];
    const int tid = threadIdx.x;
    const int bx = blockIdx.x;

    if (bx >= 1089) {
        const int tb = bx - 1089;
        const int b = tb / 172;
        const int rem = tb - b*172;
        const int ct = rem / 43;
        const int pt = rem - ct*43;
        const int c0 = ct*64, pos0 = pt*64;
        float* tile = sm;
        const float* ysrc = y + ((size_t)(b*256 + c0))*P;
        #pragma unroll
        for (int p = 0; p < 4; p++) {
            const int cr = p*16 + (tid>>4);
            const int f4 = tid&15;
            const int pos = pos0 + f4*4;
            if (pos < P) {
                const float4 v = *(const float4*)(ysrc + (size_t)cr*P + pos);
                float* d = tile + cr*65 + f4*4;
                d[0]=v.x; d[1]=v.y; d[2]=v.z; d[3]=v.w;
            }
        }
        __syncthreads();
        #pragma unroll
        for (int p = 0; p < 4; p++) {
            const int pj = p*16 + (tid>>4);
            const int c4 = tid&15;
            const int pos = pos0 + pj;
            if (pos < P) {
                float4 v;
                v.x = tile[(c4*4+0)*65 + pj];
                v.y = tile[(c4*4+1)*65 + pj];
                v.z = tile[(c4*4+2)*65 + pj];
                v.w = tile[(c4*4+3)*65 + pj];
                *(float4*)(yT + ((size_t)(b*P + pos))*256 + c0 + c4*4) = v;
            }
        }
        return;
    }
    if (bx >= 1024) {
        const int pb = bx - 1024;
        if (pb == 64) {
            float ua = 0.f, va = 0.f;
            for (int e = 0; e < 256; e++) {
                ua += qb[e] * kw[e*256 + tid];
                va += kb[e] * qw[e*256 + tid];
            }
            u[tid] = ua; v2[tid] = va;
            if (tid == 0) {
                float c = 0.f;
                for (int e = 0; e < 256; e++) c += qb[e]*kb[e];
                c0p[0] = c;
            }
            return;
        }
        const int cx0 = pb * 4;
        float (*wqs)[4] = (float(*)[4])sm;
        *(float4*)&wqs[tid][0] = *(const float4*)(qw + tid*256 + cx0);
        __syncthreads();
        float a0=0.f, a1=0.f, a2=0.f, a3=0.f;
        #pragma unroll 4
        for (int o = 0; o < 256; o++) {
            const float wk = kw[o*256 + tid];
            const float4 wq = *(const float4*)&wqs[o][0];
            a0 += wq.x*wk; a1 += wq.y*wk; a2 += wq.z*wk; a3 += wq.w*wk;
        }
        M[(cx0+0)*256 + tid] = a0;
        M[(cx0+1)*256 + tid] = a1;
        M[(cx0+2)*256 + tid] = a2;
        M[(cx0+3)*256 + tid] = a3;
        return;
    }
    const int w = tid >> 6, lane = tid & 63;
    const int pl = bx*4 + w;
    const int proj = pl >> 11;
    const int bcid = pl & 2047;
    const float* src = (proj ? y : x) + (size_t)bcid * P;
    float* plane = sm + w*P;
    {
        const float4* s4 = (const float4*)src;
        float4* p4 = (float4*)plane;
        for (int g = lane; g < 676; g += 64) p4[g] = s4[g];
    }
    __syncthreads();
    const int jh = lane >> 3, jw = lane & 7;
    const int y0 = jh*7, x0 = jw*7;
    const int ry = min(7, HW - y0), rx = min(7, HW - x0);
    float s = 0.f;
    for (int dy = 0; dy < ry; ++dy) {
        const float* row = plane + (y0 + dy)*HW + x0;
        for (int dx = 0; dx < rx; ++dx) s += row[dx];
    }
    (proj ? yr : xr)[bcid*64 + lane] = s / (float)(ry*rx);
    if (!proj) {
        const float* r0 = plane + y0*HW + x0;
        float4 g4;
        g4.x = r0[0]; g4.y = r0[1]; g4.z = r0[2];
        g4.w = (x0 + 3 < HW) ? r0[3] : 0.f;
        *(float4*)&xg[bcid*256 + lane*4] = g4;
    }
}

__global__ __launch_bounds__(256) void k2_gemms(
    const float* __restrict__ xr, const float* __restrict__ yr,
    const float* __restrict__ qw, const float* __restrict__ qb,
    const float* __restrict__ kw, const float* __restrict__ kb,
    float* __restrict__ qr, float* __restrict__ kr,
    const float* __restrict__ xg, const float* __restrict__ M,
    const float* __restrict__ u, float* __restrict__ G)
{
    __shared__ float As[32][64];
    __shared__ float Bs[32][64];
    const int tid = threadIdx.x;
    const int tx = tid & 15, ty = tid >> 4;
    float acc[4][4];
    #pragma unroll
    for (int i = 0; i < 4; i++)
        #pragma unroll
        for (int j = 0; j < 4; j++) acc[i][j] = 0.f;

    if (blockIdx.x < 64) {
        const int bp = blockIdx.x >> 2;
        const int b = bp >> 1, proj = bp & 1;
        const float* X = (proj ? yr : xr) + b*C*64;
        const float* W = proj ? kw : qw;
        const float* Bv = proj ? kb : qb;
        float* O = (proj ? kr : qr) + b*C*64;
        const int o0 = (blockIdx.x & 3) * 64;
        const int aor = tid & 63;
        const int akc = (tid >> 6) * 8;
        const int bkr = tid >> 3;
        const int bjc = (tid & 7) * 8;
        for (int k0 = 0; k0 < 256; k0 += 32) {
            const float4 w0 = *(const float4*)(W + (o0 + aor)*256 + k0 + akc);
            const float4 w1 = *(const float4*)(W + (o0 + aor)*256 + k0 + akc + 4);
            const float4 x0v = *(const float4*)(X + (k0 + bkr)*64 + bjc);
            const float4 x1v = *(const float4*)(X + (k0 + bkr)*64 + bjc + 4);
            __syncthreads();
            As[akc+0][aor] = w0.x; As[akc+1][aor] = w0.y; As[akc+2][aor] = w0.z; As[akc+3][aor] = w0.w;
            As[akc+4][aor] = w1.x; As[akc+5][aor] = w1.y; As[akc+6][aor] = w1.z; As[akc+7][aor] = w1.w;
            *(float4*)&Bs[bkr][bjc] = x0v;
            *(float4*)&Bs[bkr][bjc+4] = x1v;
            __syncthreads();
            #pragma unroll
            for (int kk = 0; kk < 32; kk++) {
                const float4 a = *(const float4*)&As[kk][ty*4];
                const float4 bb = *(const float4*)&Bs[kk][tx*4];
                const float av[4] = {a.x, a.y, a.z, a.w};
                const float bv[4] = {bb.x, bb.y, bb.z, bb.w};
                #pragma unroll
                for (int i = 0; i < 4; i++)
                    #pragma unroll
                    for (int j = 0; j < 4; j++) acc[i][j] += av[i]*bv[j];
            }
        }
        #pragma unroll
        for (int i = 0; i < 4; i++) {
            const int o = o0 + ty*4 + i;
            const float bias = Bv[o];
            float4 ov;
            ov.x = acc[i][0]+bias; ov.y = acc[i][1]+bias;
            ov.z = acc[i][2]+bias; ov.w = acc[i][3]+bias;
            *(float4*)(O + o*64 + tx*4) = ov;
        }
    } else {
        const int id2 = blockIdx.x - 64;
        const int b = id2 >> 4, sub = id2 & 15;
        const int p0 = (sub >> 2)*64, o0 = (sub & 3)*64;
        const float* Xg = xg + b*C*256;
        float* Gb = G + b*256*256;
        const int lkr = tid >> 3;
        const int ljc = (tid & 7) * 8;
        for (int k0 = 0; k0 < 256; k0 += 32) {
            const float4 a0 = *(const float4*)(Xg + (k0 + lkr)*256 + p0 + ljc);
            const float4 a1 = *(const float4*)(Xg + (k0 + lkr)*256 + p0 + ljc + 4);
            const float4 b0 = *(const float4*)(M + (k0 + lkr)*256 + o0 + ljc);
            const float4 b1 = *(const float4*)(M + (k0 + lkr)*256 + o0 + ljc + 4);
            __syncthreads();
            *(float4*)&As[lkr][ljc] = a0; *(float4*)&As[lkr][ljc+4] = a1;
            *(float4*)&Bs[lkr][ljc] = b0; *(float4*)&Bs[lkr][ljc+4] = b1;
            __syncthreads();
            #pragma unroll
            for (int kk = 0; kk < 32; kk++) {
                const float4 a = *(const float4*)&As[kk][ty*4];
                const float4 bb = *(const float4*)&Bs[kk][tx*4];
                const float av[4] = {a.x, a.y, a.z, a.w};
                const float bv[4] = {bb.x, bb.y, bb.z, bb.w};
                #pragma unroll
                for (int i = 0; i < 4; i++)
                    #pragma unroll
                    for (int j = 0; j < 4; j++) acc[i][j] += av[i]*bv[j];
            }
        }
        const float4 u4 = *(const float4*)(u + o0 + tx*4);
        #pragma unroll
        for (int i = 0; i < 4; i++) {
            float4 ov;
            ov.x = acc[i][0]+u4.x; ov.y = acc[i][1]+u4.y;
            ov.z = acc[i][2]+u4.z; ov.w = acc[i][3]+u4.w;
            *(float4*)(Gb + (p0 + ty*4 + i)*256 + o0 + tx*4) = ov;
        }
    }
}

__global__ __launch_bounds__(256) void k3_topk_vals(
    const float* __restrict__ yT, const float* __restrict__ qr,
    const float* __restrict__ kr, const float* __restrict__ G,
    const float* __restrict__ xg, const float* __restrict__ v2,
    const float* __restrict__ c0p,
    float* __restrict__ arT, int* __restrict__ idxout, float* __restrict__ vals)
{
    const int b = blockIdx.y, r = blockIdx.x;
    __shared__ float pdot[4][64];
    __shared__ float Gs[4][256];
    __shared__ float Hs[4];
    __shared__ int gsh;
    __shared__ float Ys[49][260];
    const int tid = threadIdx.x, w = tid >> 6, lane = tid & 63;
    {
        const float* qcol = qr + b*C*64 + r;
        const float* kcol = kr + b*C*64 + lane;
        float d = 0.f;
        #pragma unroll 8
        for (int cc = 0; cc < 64; cc++) {
            const int c = w*64 + cc;
            d += qcol[c*64] * kcol[c*64];
        }
        pdot[w][lane] = d;
    }
    *(float4*)&Gs[w][lane*4] = *(const float4*)(G + ((b*256 + r*4 + w)*256) + lane*4);
    {
        const int pos = r*4 + w;
        float acc = 0.f;
        #pragma unroll
        for (int cc = 0; cc < 4; cc++) {
            const int c = lane + cc*64;
            acc += xg[(b*256 + c)*256 + pos] * v2[c];
        }
        #pragma unroll
        for (int off = 32; off >= 1; off >>= 1) acc += __shfl_xor(acc, off);
        if (lane == 0) Hs[w] = acc + c0p[0];
    }
    __syncthreads();
    if (w == 0) {
        const float dot = pdot[0][lane] + pdot[1][lane] + pdot[2][lane] + pdot[3][lane];
        arT[(b*64 + lane)*64 + r] = dot * SCALE;
        float v = dot;
        const int my = lane;
        #pragma unroll
        for (int t = 0; t < NTOPK; t++) {
            float bv = v; int bi = my;
            #pragma unroll
            for (int off = 32; off >= 1; off >>= 1) {
                const float ov = __shfl_xor(bv, off);
                const int   oi = __shfl_xor(bi, off);
                if (ov > bv || (ov == bv && oi < bi)) { bv = ov; bi = oi; }
            }
            if (lane == 0) {
                idxout[(b*64 + r)*NTOPK + t] = bi;
                if (t == NTOPK-1) gsh = bi;
            }
            if (my == bi) v = -3.0e38f;
        }
    }
    __syncthreads();
    const int g = gsh;
    const int gy = g >> 3, gx = g & 7;
    for (int i = tid; i < 49*64; i += 256) {
        const int k2 = i >> 6, f4 = i & 63;
        const int dy = d7(k2), dx = k2 - dy*7;
        const int kY = gy*7 + dy, kX = gx*7 + dx;
        float4 v = make_float4(0.f, 0.f, 0.f, 0.f);
        if (kY < HW && kX < HW)
            v = *(const float4*)(yT + ((size_t)(b*P + kY*HW + kX))*256 + f4*4);
        *(float4*)&Ys[k2][f4*4] = v;
    }
    __syncthreads();
    if (tid < NTOPK*49) {
        const int t = tid / 49, k2 = tid % 49;
        const int qX = (r & 7)*7 + t;
        const int dy = d7(k2), dx = k2 - dy*7;
        const int kY = gy*7 + dy, kX = gx*7 + dx;
        float res = 0.f;
        if (qX < HW && kY < HW && kX < HW) {
            const float4* Gp = (const float4*)&Gs[t][0];
            const float4* Yp = (const float4*)&Ys[k2][0];
            float dot = 0.f;
            #pragma unroll 8
            for (int cc = 0; cc < 64; cc++) {
                const float4 a = Gp[cc], yy = Yp[cc];
                dot += a.x*yy.x + a.y*yy.y + a.z*yy.z + a.w*yy.w;
            }
            res = SCALE * (dot + Hs[t]);
        }
        vals[((b*64 + r)*NTOPK + t)*49 + k2] = res;
    }
}

__global__ __launch_bounds__(256) void fill_kernel(
    const float* __restrict__ arT, const float* __restrict__ vals,
    const int* __restrict__ idx, float* __restrict__ out)
{
    const int b = blockIdx.y;
    const int yx = blockIdx.x;
    const int Y1 = yx / HW, X1 = yx % HW;
    const int r1 = (Y1/7)*8 + X1/7;
    const int q1 = (Y1%7)*7 + X1%7;
    const int p2 = r1*49 + q1;
    const int yy = p2/56, xx = p2 - 56*yy;
    const int regB = (yy/7)*8 + xx/7;
    __shared__ float acol[64];
    __shared__ float vrow[49];
    const int tid = threadIdx.x;
    if (tid < 64) acol[tid] = arT[(b*64 + regB)*64 + tid];
    int ovr = -1;
    if (q1 < NTOPK) {
        ovr = idx[(b*64 + r1)*NTOPK + q1];
        if (tid < 49) vrow[tid] = vals[((b*64 + r1)*NTOPK + q1)*49 + tid];
    }
    __syncthreads();
    float* plane = out + (size_t)(b*P + yx) * P;
    for (int u = tid; u < 676; u += 256) {
        const int Y2 = d13(u);
        const int g4 = u - Y2*13;
        const int X2b = g4*4;
        const int ry2 = d7(Y2);
        const int my2 = Y2 - ry2*7;
        float res[4];
        #pragma unroll
        for (int j = 0; j < 4; j++) {
            const int X2 = X2b + j;
            const int rx2 = d7(X2);
            const int mx2 = X2 - rx2*7;
            const int r2 = ry2*8 + rx2;
            const int k2 = my2*7 + mx2;
            const int P1 = r2*49 + k2;
            const int Yp = d56(P1);
            const int Xp = P1 - Yp*56;
            const int regA = d7(Yp)*8 + d7(Xp);
            float v = acol[regA];
            if (r2 == ovr) v = vrow[k2];
            res[j] = v;
        }
        float4 o; o.x = res[0]; o.y = res[1]; o.z = res[2]; o.w = res[3];
        *(float4*)(plane + Y2*HW + X2b) = o;
    }
}

extern "C" void kernel_launch(void* const* d_in, const int* in_sizes, int n_in,
                              void* d_out, int out_size, void* d_ws, size_t ws_size,
                              hipStream_t stream)
{
    const float* x  = (const float*)d_in[0];
    const float* y  = (const float*)d_in[1];
    const float* qw = (const float*)d_in[2];
    const float* qb = (const float*)d_in[3];
    const float* kw = (const float*)d_in[4];
    const float* kb = (const float*)d_in[5];
    float* out = (float*)d_out;
    float* ws  = (float*)d_ws;

    const float* xp = x; const float* yp = y;
    const float* qwp = qw; const float* qbp = qb;
    const float* kwp = kw; const float* kbp = kb;
    float* outp = out; float* wsp = ws;
    void* args[8] = { (void*)&xp, (void*)&yp, (void*)&qwp, (void*)&qbp,
                      (void*)&kwp, (void*)&kbp, (void*)&outp, (void*)&wsp };

    hipError_t err = hipLaunchCooperativeKernel(
        reinterpret_cast<const void*>(&mega), dim3(512), dim3(256),
        args, 0u, stream);

    if (err != hipSuccess) {
        // Fallback: proven 4-kernel pipeline (R4 layout)
        float* xr  = out;
        float* yr  = xr + 131072;
        float* qr  = yr + 131072;
        float* kr  = qr + 131072;
        float* xg  = kr + 131072;
        float* G   = xg + 524288;
        float* M   = G  + 524288;
        float* u   = M  + 65536;
        float* v2  = u  + 256;
        float* c0p = v2 + 256;
        float* yT  = c0p + 16;
        float* arT = ws;
        float* vls = arT + 32768;
        int*   idx = (int*)(vls + 100352);

        k1_pool_prep_tr<<<2465, 256, 0, stream>>>(x, y, qw, qb, kw, kb, xr, yr, xg,
                                                  M, u, v2, c0p, yT);
        k2_gemms<<<192, 256, 0, stream>>>(xr, yr, qw, qb, kw, kb, qr, kr, xg, M, u, G);
        k3_topk_vals<<<dim3(64, 8), 256, 0, stream>>>(yT, qr, kr, G, xg, v2, c0p, arT, idx, vls);
        fill_kernel<<<dim3(P, 8), 256, 0, stream>>>(arT, vls, idx, out);
    }
}

// Round 6
// 116.726 us; speedup vs baseline: 2.7510x; 2.7510x over previous
//
#include <hip/hip_runtime.h>

#define NB 8
#define C 256
#define HW 52
#define P (HW*HW)            // 2704
#define NTOPK 4
#define SCALE 0.0625f

// exact unsigned div helpers (verified ranges)
static __device__ __forceinline__ int d7(int v)  { return (v*9363) >> 16; }   // v <= 3135
static __device__ __forceinline__ int d56(int v) { return (v*18725) >> 20; }  // v <= 3135
static __device__ __forceinline__ int d13(int v) { return (v*10083) >> 17; }  // v <= 675

// scratch layout (floats) at front of d_out
#define OFF_YR  0               // 8*256*64   = 131072   [b][c][reg]
#define OFF_XGT 131072          // 8*256*256  = 524288   [b][pos][c]
#define OFF_XRT 655360          // 8*64*256   = 131072   [b][reg][c]
#define OFF_M   786432          // 65536
#define OFF_U   851968          // 256
#define OFF_V2  852224          // 256
#define OFF_C0  852480          // 16
#define OFF_YT  852496          // 8*2704*256 = 5537792  [b][pos][c]

// ============ K1: blocks 0..1023 pool (xrT,xgT,yr); 1024..1088 prep (M,u,v2,c0);
//              1089..2464 y NCHW->N(HW)C transpose into yT ==================
__global__ __launch_bounds__(256) void k1_pool_prep_tr(
    const float* __restrict__ x, const float* __restrict__ y,
    const float* __restrict__ qw, const float* __restrict__ qb,
    const float* __restrict__ kw, const float* __restrict__ kb,
    float* __restrict__ scr)
{
    __shared__ float sm[4*P];           // 43.3 KB
    const int tid = threadIdx.x;
    const int bx = blockIdx.x;

    float* yr  = scr + OFF_YR;
    float* xgT = scr + OFF_XGT;
    float* xrT = scr + OFF_XRT;
    float* M   = scr + OFF_M;
    float* u   = scr + OFF_U;
    float* v2  = scr + OFF_V2;
    float* c0p = scr + OFF_C0;
    float* yT  = scr + OFF_YT;

    if (bx >= 1089) {                   // ---- transpose path: 64c x 64pos tile ----
        const int tb = bx - 1089;
        const int b = tb / 172;
        const int rem = tb - b*172;
        const int ct = rem / 43;
        const int pt = rem - ct*43;
        const int c0 = ct*64, pos0 = pt*64;
        float* tile = sm;               // [64][65]
        const float* ysrc = y + ((size_t)(b*256 + c0))*P;
        #pragma unroll
        for (int p = 0; p < 4; p++) {
            const int cr = p*16 + (tid>>4);
            const int f4 = tid&15;
            const int pos = pos0 + f4*4;
            if (pos < P) {
                const float4 v = *(const float4*)(ysrc + (size_t)cr*P + pos);
                float* d = tile + cr*65 + f4*4;
                d[0]=v.x; d[1]=v.y; d[2]=v.z; d[3]=v.w;
            }
        }
        __syncthreads();
        #pragma unroll
        for (int p = 0; p < 4; p++) {
            const int pj = p*16 + (tid>>4);
            const int c4 = tid&15;
            const int pos = pos0 + pj;
            if (pos < P) {
                float4 v;
                v.x = tile[(c4*4+0)*65 + pj];
                v.y = tile[(c4*4+1)*65 + pj];
                v.z = tile[(c4*4+2)*65 + pj];
                v.w = tile[(c4*4+3)*65 + pj];
                *(float4*)(yT + ((size_t)(b*P + pos))*256 + c0 + c4*4) = v;
            }
        }
        return;
    }

    if (bx >= 1024) {                   // ---- prep path ----
        const int pb = bx - 1024;
        if (pb == 64) {
            float ua = 0.f, va = 0.f;
            for (int e = 0; e < 256; e++) {
                ua += qb[e] * kw[e*256 + tid];
                va += kb[e] * qw[e*256 + tid];
            }
            u[tid] = ua; v2[tid] = va;
            if (tid == 0) {
                float c = 0.f;
                for (int e = 0; e < 256; e++) c += qb[e]*kb[e];
                c0p[0] = c;
            }
            return;
        }
        const int cx0 = pb * 4;
        float (*wqs)[4] = (float(*)[4])sm;
        *(float4*)&wqs[tid][0] = *(const float4*)(qw + tid*256 + cx0);
        __syncthreads();
        float a0=0.f, a1=0.f, a2=0.f, a3=0.f;
        #pragma unroll 4
        for (int o = 0; o < 256; o++) {
            const float wk = kw[o*256 + tid];
            const float4 wq = *(const float4*)&wqs[o][0];
            a0 += wq.x*wk; a1 += wq.y*wk; a2 += wq.z*wk; a3 += wq.w*wk;
        }
        M[(cx0+0)*256 + tid] = a0;
        M[(cx0+1)*256 + tid] = a1;
        M[(cx0+2)*256 + tid] = a2;
        M[(cx0+3)*256 + tid] = a3;
        return;
    }

    // ---- pool path: wave w handles plane bx*4+w ----
    const int w = tid >> 6, lane = tid & 63;
    const int pl = bx*4 + w;
    const int proj = pl >> 11;
    const int bcid = pl & 2047;                     // b*256 + c
    const int bb = bcid >> 8, cc = bcid & 255;
    const float* src = (proj ? y : x) + (size_t)bcid * P;
    float* plane = sm + w*P;
    {   // vectorized plane load: 676 float4
        const float4* s4 = (const float4*)src;
        float4* p4 = (float4*)plane;
        for (int g = lane; g < 676; g += 64) p4[g] = s4[g];
    }
    __syncthreads();
    const int jh = lane >> 3, jw = lane & 7;
    const int y0 = jh*7, x0 = jw*7;
    const int ry = min(7, HW - y0), rx = min(7, HW - x0);
    float s = 0.f;
    for (int dy = 0; dy < ry; ++dy) {
        const float* row = plane + (y0 + dy)*HW + x0;
        for (int dx = 0; dx < rx; ++dx) s += row[dx];
    }
    const float pooled = s / (float)(ry*rx);
    if (proj) {
        yr[bcid*64 + lane] = pooled;                // [b][c][reg]
    } else {
        xrT[((size_t)(bb*64) + lane)*256 + cc] = pooled;   // [b][reg][c]
        const float* r0 = plane + y0*HW + x0;
        #pragma unroll
        for (int t = 0; t < 4; t++) {
            const float v = (x0 + t < HW) ? r0[t] : 0.f;
            xgT[((size_t)(bb*256) + lane*4 + t)*256 + cc] = v;  // [b][pos][c]
        }
    }
}

// ============ K2: per (b,r): local row-GEMM (G rows + Gr) + a_r row + top-4 + vals
__global__ __launch_bounds__(256) void k2_topk_vals(
    const float* __restrict__ scr,
    float* __restrict__ arT, int* __restrict__ idxout, float* __restrict__ vals)
{
    const int b = blockIdx.y, r = blockIdx.x;
    const int tid = threadIdx.x, w = tid >> 6, lane = tid & 63;

    const float* yr  = scr + OFF_YR;
    const float* xgT = scr + OFF_XGT;
    const float* xrT = scr + OFF_XRT;
    const float* M   = scr + OFF_M;
    const float* u   = scr + OFF_U;
    const float* v2  = scr + OFF_V2;
    const float* c0p = scr + OFF_C0;
    const float* yT  = scr + OFF_YT;

    __shared__ float Gs[4][256];    // G rows for pos r*4+t
    __shared__ float Grs[256];      // Gr row r
    __shared__ float pdot[4][64];
    __shared__ float aux[12];       // [0..3]=H[t], [4..7]=ci partials
    __shared__ int gsh;
    __shared__ float Ys[49][260];

    // Phase A: row-GEMM — thread owns column o = tid; 5 accumulators.
    const float* xrow0 = xgT + ((size_t)(b*256) + r*4)*256;   // 4 rows, contiguous
    const float* xrow4 = xrT + ((size_t)(b*64) + r)*256;
    {
        float a0=0.f, a1=0.f, a2=0.f, a3=0.f, a4=0.f;
        #pragma unroll 4
        for (int c = 0; c < 256; c++) {
            const float m = M[c*256 + tid];       // coalesced 1KB/wave
            a0 += xrow0[c]       * m;             // wave-uniform (scalar) operands
            a1 += xrow0[256 + c] * m;
            a2 += xrow0[512 + c] * m;
            a3 += xrow0[768 + c] * m;
            a4 += xrow4[c]       * m;
        }
        const float uo = u[tid];
        Gs[0][tid] = a0 + uo;
        Gs[1][tid] = a1 + uo;
        Gs[2][tid] = a2 + uo;
        Gs[3][tid] = a3 + uo;
        Grs[tid]   = a4 + uo;
    }
    // H[t] (warp w handles t=w) and ci partials
    {
        const float* xh = xrow0 + w*256;
        float hacc = 0.f;
        #pragma unroll
        for (int j = 0; j < 4; j++) {
            const int c = lane + j*64;
            hacc += xh[c] * v2[c];
        }
        #pragma unroll
        for (int off = 32; off >= 1; off >>= 1) hacc += __shfl_xor(hacc, off);
        if (lane == 0) aux[w] = hacc + c0p[0];

        float cacc = xrow4[w*64 + lane] * v2[w*64 + lane];
        #pragma unroll
        for (int off = 32; off >= 1; off >>= 1) cacc += __shfl_xor(cacc, off);
        if (lane == 0) aux[4 + w] = cacc;
    }
    __syncthreads();

    // Phase B: a_r row — warp w covers c-chunk w
    {
        const float* yrB = yr + b*C*64;
        float d = 0.f;
        #pragma unroll 8
        for (int cc = 0; cc < 64; cc++) {
            const int c = w*64 + cc;
            d += Grs[c] * yrB[c*64 + lane];
        }
        pdot[w][lane] = d;
    }
    __syncthreads();

    // warp 0: full dot, arT write, top-4 (low-index tie-break)
    if (w == 0) {
        const float ci = aux[4] + aux[5] + aux[6] + aux[7] + c0p[0];
        const float dot = pdot[0][lane] + pdot[1][lane] + pdot[2][lane]
                        + pdot[3][lane] + ci;
        arT[(b*64 + lane)*64 + r] = dot * SCALE;
        float v = dot;
        const int my = lane;
        #pragma unroll
        for (int t = 0; t < NTOPK; t++) {
            float bv = v; int bi = my;
            #pragma unroll
            for (int off = 32; off >= 1; off >>= 1) {
                const float ov = __shfl_xor(bv, off);
                const int   oi = __shfl_xor(bi, off);
                if (ov > bv || (ov == bv && oi < bi)) { bv = ov; bi = oi; }
            }
            if (lane == 0) {
                idxout[(b*64 + r)*NTOPK + t] = bi;
                if (t == NTOPK-1) gsh = bi;
            }
            if (my == bi) v = -3.0e38f;
        }
    }
    __syncthreads();

    // Phase C: stage yT rows for region g into LDS [k2][c] — coalesced float4
    const int g = gsh;
    const int gy = g >> 3, gx = g & 7;
    for (int i = tid; i < 49*64; i += 256) {
        const int k2 = i >> 6, f4 = i & 63;
        const int dy = d7(k2), dx = k2 - dy*7;
        const int kY = gy*7 + dy, kX = gx*7 + dx;
        float4 v = make_float4(0.f, 0.f, 0.f, 0.f);
        if (kY < HW && kX < HW)
            v = *(const float4*)(yT + ((size_t)(b*P + kY*HW + kX))*256 + f4*4);
        *(float4*)&Ys[k2][f4*4] = v;
    }
    __syncthreads();

    // Phase E: vals[b,r,t,k2] = SCALE*(G_row . y_col + H)
    if (tid < NTOPK*49) {
        const int t = tid / 49, k2 = tid - (tid/49)*49;
        const int qX = (r & 7)*7 + t;
        const int dy = d7(k2), dx = k2 - dy*7;
        const int kY = gy*7 + dy, kX = gx*7 + dx;
        float res = 0.f;
        if (qX < HW && kY < HW && kX < HW) {
            const float4* Gp = (const float4*)&Gs[t][0];
            const float4* Yp = (const float4*)&Ys[k2][0];
            float dot = 0.f;
            #pragma unroll 8
            for (int cc = 0; cc < 64; cc++) {
                const float4 a = Gp[cc], yy = Yp[cc];
                dot += a.x*yy.x + a.y*yy.y + a.z*yy.z + a.w*yy.w;
            }
            res = SCALE * (dot + aux[t]);
        }
        vals[((b*64 + r)*NTOPK + t)*49 + k2] = res;
    }
}

// ============ K3: final fill — one block per (b, Y1, X1) =====================
__global__ __launch_bounds__(256) void fill_kernel(
    const float* __restrict__ arT, const float* __restrict__ vals,
    const int* __restrict__ idx, float* __restrict__ out)
{
    const int b = blockIdx.y;
    const int yx = blockIdx.x;            // Y1*52 + X1
    const int Y1 = yx / HW, X1 = yx % HW;
    const int r1 = (Y1/7)*8 + X1/7;
    const int q1 = (Y1%7)*7 + X1%7;
    const int p2 = r1*49 + q1;
    const int yy = p2/56, xx = p2 - 56*yy;
    const int regB = (yy/7)*8 + xx/7;

    __shared__ float acol[64];
    __shared__ float vrow[49];
    const int tid = threadIdx.x;
    if (tid < 64) acol[tid] = arT[(b*64 + regB)*64 + tid];
    int ovr = -1;
    if (q1 < NTOPK) {
        ovr = idx[(b*64 + r1)*NTOPK + q1];
        if (tid < 49) vrow[tid] = vals[((b*64 + r1)*NTOPK + q1)*49 + tid];
    }
    __syncthreads();

    float* plane = out + (size_t)(b*P + yx) * P;
    for (int u = tid; u < 676; u += 256) {       // 676 = 52*13 float4 groups
        const int Y2 = d13(u);
        const int g4 = u - Y2*13;
        const int X2b = g4*4;
        const int ry2 = d7(Y2);
        const int my2 = Y2 - ry2*7;
        float res[4];
        #pragma unroll
        for (int j = 0; j < 4; j++) {
            const int X2 = X2b + j;
            const int rx2 = d7(X2);
            const int mx2 = X2 - rx2*7;
            const int r2 = ry2*8 + rx2;
            const int k2 = my2*7 + mx2;
            const int P1 = r2*49 + k2;
            const int Yp = d56(P1);
            const int Xp = P1 - Yp*56;
            const int regA = d7(Yp)*8 + d7(Xp);
            float v = acol[regA];
            if (r2 == ovr) v = vrow[k2];
            res[j] = v;
        }
        float4 o; o.x = res[0]; o.y = res[1]; o.z = res[2]; o.w = res[3];
        *(float4*)(plane + Y2*HW + X2b) = o;
    }
}

extern "C" void kernel_launch(void* const* d_in, const int* in_sizes, int n_in,
                              void* d_out, int out_size, void* d_ws, size_t ws_size,
                              hipStream_t stream)
{
    const float* x  = (const float*)d_in[0];
    const float* y  = (const float*)d_in[1];
    const float* qw = (const float*)d_in[2];
    const float* qb = (const float*)d_in[3];
    const float* kw = (const float*)d_in[4];
    const float* kb = (const float*)d_in[5];
    float* out = (float*)d_out;

    // Large scratch at front of d_out (~25.6 MB << 234 MB out buffer);
    // fully consumed by k2 before fill_kernel overwrites d_out.
    float* scr = out;

    // fill-consumed small arrays stay in d_ws
    float* ws  = (float*)d_ws;
    float* arT = ws;                          // 8*64*64 = 32768
    float* vls = arT + 32768;                 // 8*64*4*49 = 100352
    int*   idx = (int*)(vls + 100352);        // 8*64*4 ints

    k1_pool_prep_tr<<<2465, 256, 0, stream>>>(x, y, qw, qb, kw, kb, scr);
    k2_topk_vals<<<dim3(64, 8), 256, 0, stream>>>(scr, arT, idx, vls);
    fill_kernel<<<dim3(P, 8), 256, 0, stream>>>(arT, vls, idx, out);
}

// Round 8
// 106.537 us; speedup vs baseline: 3.0141x; 1.0956x over previous
//
#include <hip/hip_runtime.h>

#define NB 8
#define C 256
#define HW 52
#define P (HW*HW)            // 2704
#define NTOPK 4
#define SCALE 0.0625f

typedef float nt_f32x4 __attribute__((ext_vector_type(4)));

// exact unsigned div helpers (verified ranges)
static __device__ __forceinline__ int d7(int v)  { return (v*9363) >> 16; }   // v <= 3135
static __device__ __forceinline__ int d56(int v) { return (v*18725) >> 20; }  // v <= 3135
static __device__ __forceinline__ int d13(int v) { return (v*10083) >> 17; }  // v <= 675

// scratch layout (floats) at front of d_out
#define OFF_XR  0               // 8*256*64   = 131072   [b][c][reg]
#define OFF_YR  131072          // 131072                [b][c][reg]
#define OFF_XG  262144          // 8*256*256  = 524288   [b][c][pos]
#define OFF_G   786432          // 8*256*256  = 524288   [b][pos][o]
#define OFF_GR  1310720         // 8*64*256   = 131072   [b][reg][o]
#define OFF_M   1441792         // 65536
#define OFF_U   1507328         // 256
#define OFF_V2  1507584         // 256
#define OFF_C0  1507840         // 16
#define OFF_YT  1507856         // 8*2704*256 = 5537792  [b][pos][c]

// ============ K1: blocks 0..1023 pool (xr,yr,xg); 1024..1088 prep (M,u,v2,c0);
//              1089..2464 y NCHW->N(HW)C transpose into yT ==================
__global__ __launch_bounds__(256) void k1_pool_prep_tr(
    const float* __restrict__ x, const float* __restrict__ y,
    const float* __restrict__ qw, const float* __restrict__ qb,
    const float* __restrict__ kw, const float* __restrict__ kb,
    float* __restrict__ scr)
{
    __shared__ float sm[4*P];           // 43.3 KB
    const int tid = threadIdx.x;
    const int bx = blockIdx.x;

    float* xr  = scr + OFF_XR;
    float* yr  = scr + OFF_YR;
    float* xg  = scr + OFF_XG;
    float* M   = scr + OFF_M;
    float* u   = scr + OFF_U;
    float* v2  = scr + OFF_V2;
    float* c0p = scr + OFF_C0;
    float* yT  = scr + OFF_YT;

    if (bx >= 1089) {                   // ---- transpose path: 64c x 64pos tile ----
        const int tb = bx - 1089;
        const int b = tb / 172;
        const int rem = tb - b*172;
        const int ct = rem / 43;
        const int pt = rem - ct*43;
        const int c0 = ct*64, pos0 = pt*64;
        float* tile = sm;               // [64][65]
        const float* ysrc = y + ((size_t)(b*256 + c0))*P;
        #pragma unroll
        for (int p = 0; p < 4; p++) {
            const int cr = p*16 + (tid>>4);
            const int f4 = tid&15;
            const int pos = pos0 + f4*4;
            if (pos < P) {
                const float4 v = *(const float4*)(ysrc + (size_t)cr*P + pos);
                float* d = tile + cr*65 + f4*4;
                d[0]=v.x; d[1]=v.y; d[2]=v.z; d[3]=v.w;
            }
        }
        __syncthreads();
        #pragma unroll
        for (int p = 0; p < 4; p++) {
            const int pj = p*16 + (tid>>4);
            const int c4 = tid&15;
            const int pos = pos0 + pj;
            if (pos < P) {
                float4 v;
                v.x = tile[(c4*4+0)*65 + pj];
                v.y = tile[(c4*4+1)*65 + pj];
                v.z = tile[(c4*4+2)*65 + pj];
                v.w = tile[(c4*4+3)*65 + pj];
                *(float4*)(yT + ((size_t)(b*P + pos))*256 + c0 + c4*4) = v;
            }
        }
        return;
    }

    if (bx >= 1024) {                   // ---- prep path ----
        const int pb = bx - 1024;
        if (pb == 64) {
            float ua = 0.f, va = 0.f;
            for (int e = 0; e < 256; e++) {
                ua += qb[e] * kw[e*256 + tid];
                va += kb[e] * qw[e*256 + tid];
            }
            u[tid] = ua; v2[tid] = va;
            if (tid == 0) {
                float c = 0.f;
                for (int e = 0; e < 256; e++) c += qb[e]*kb[e];
                c0p[0] = c;
            }
            return;
        }
        const int cx0 = pb * 4;
        float (*wqs)[4] = (float(*)[4])sm;
        *(float4*)&wqs[tid][0] = *(const float4*)(qw + tid*256 + cx0);
        __syncthreads();
        float a0=0.f, a1=0.f, a2=0.f, a3=0.f;
        #pragma unroll 4
        for (int o = 0; o < 256; o++) {
            const float wk = kw[o*256 + tid];
            const float4 wq = *(const float4*)&wqs[o][0];
            a0 += wq.x*wk; a1 += wq.y*wk; a2 += wq.z*wk; a3 += wq.w*wk;
        }
        M[(cx0+0)*256 + tid] = a0;
        M[(cx0+1)*256 + tid] = a1;
        M[(cx0+2)*256 + tid] = a2;
        M[(cx0+3)*256 + tid] = a3;
        return;
    }

    // ---- pool path: wave w handles plane bx*4+w ----
    const int w = tid >> 6, lane = tid & 63;
    const int pl = bx*4 + w;
    const int proj = pl >> 11;
    const int bcid = pl & 2047;                     // b*256 + c
    const float* src = (proj ? y : x) + (size_t)bcid * P;
    float* plane = sm + w*P;
    {   // vectorized plane load: 676 float4
        const float4* s4 = (const float4*)src;
        float4* p4 = (float4*)plane;
        for (int g = lane; g < 676; g += 64) p4[g] = s4[g];
    }
    __syncthreads();
    const int jh = lane >> 3, jw = lane & 7;
    const int y0 = jh*7, x0 = jw*7;
    const int ry = min(7, HW - y0), rx = min(7, HW - x0);
    float s = 0.f;
    for (int dy = 0; dy < ry; ++dy) {
        const float* row = plane + (y0 + dy)*HW + x0;
        for (int dx = 0; dx < rx; ++dx) s += row[dx];
    }
    const float pooled = s / (float)(ry*rx);
    if (proj) {
        yr[bcid*64 + lane] = pooled;
    } else {
        xr[bcid*64 + lane] = pooled;
        const float* r0 = plane + y0*HW + x0;
        float4 g4;
        g4.x = r0[0]; g4.y = r0[1]; g4.z = r0[2];
        g4.w = (x0 + 3 < HW) ? r0[3] : 0.f;
        *(float4*)&xg[bcid*256 + lane*4] = g4;
    }
}

// ============ K2: 160 blocks: b(8) x {ptile 0..3 -> G, ptile 4 -> Gr} x otile(4)
__global__ __launch_bounds__(256) void k2_gemms(float* __restrict__ scr)
{
    const float* xr = scr + OFF_XR;
    const float* xg = scr + OFF_XG;
    float* G  = scr + OFF_G;
    float* Gr = scr + OFF_GR;
    const float* M  = scr + OFF_M;
    const float* uu = scr + OFF_U;

    __shared__ float As[32][64];
    __shared__ float Bs[32][64];
    const int tid = threadIdx.x;
    const int tx = tid & 15, ty = tid >> 4;

    const int un = blockIdx.x;
    const int b = un / 20;
    const int rem = un - b*20;
    const int pt = rem >> 2, ot = rem & 3;
    const int o0 = ot*64;

    float acc[4][4];
    #pragma unroll
    for (int i = 0; i < 4; i++)
        #pragma unroll
        for (int j = 0; j < 4; j++) acc[i][j] = 0.f;

    const int lkr = tid >> 3;
    const int ljc = (tid & 7) * 8;
    const float* Asrc; int astr;
    if (pt < 4) { Asrc = xg + (size_t)b*C*256 + pt*64; astr = 256; }
    else        { Asrc = xr + (size_t)b*C*64;          astr = 64;  }

    for (int k0 = 0; k0 < 256; k0 += 32) {
        const float4 a0 = *(const float4*)(Asrc + (size_t)(k0 + lkr)*astr + ljc);
        const float4 a1 = *(const float4*)(Asrc + (size_t)(k0 + lkr)*astr + ljc + 4);
        const float4 b0 = *(const float4*)(M + (k0 + lkr)*256 + o0 + ljc);
        const float4 b1 = *(const float4*)(M + (k0 + lkr)*256 + o0 + ljc + 4);
        __syncthreads();
        *(float4*)&As[lkr][ljc] = a0; *(float4*)&As[lkr][ljc+4] = a1;
        *(float4*)&Bs[lkr][ljc] = b0; *(float4*)&Bs[lkr][ljc+4] = b1;
        __syncthreads();
        #pragma unroll
        for (int kk = 0; kk < 32; kk++) {
            const float4 a = *(const float4*)&As[kk][ty*4];
            const float4 bb = *(const float4*)&Bs[kk][tx*4];
            const float av[4] = {a.x, a.y, a.z, a.w};
            const float bv[4] = {bb.x, bb.y, bb.z, bb.w};
            #pragma unroll
            for (int i = 0; i < 4; i++)
                #pragma unroll
                for (int j = 0; j < 4; j++) acc[i][j] += av[i]*bv[j];
        }
    }
    const float4 u4 = *(const float4*)(uu + o0 + tx*4);
    float* base = (pt < 4) ? (G + ((size_t)b*256 + pt*64)*256)
                           : (Gr + (size_t)b*64*256);
    #pragma unroll
    for (int i = 0; i < 4; i++) {
        float4 ov;
        ov.x = acc[i][0]+u4.x; ov.y = acc[i][1]+u4.y;
        ov.z = acc[i][2]+u4.z; ov.w = acc[i][3]+u4.w;
        *(float4*)(base + (ty*4 + i)*256 + o0 + tx*4) = ov;
    }
}

// ============ K3: per (b,r): a_r row (Gr.yr) + top-4 + vals (yT staged) =====
__global__ __launch_bounds__(256) void k3_topk_vals(
    const float* __restrict__ scr,
    float* __restrict__ arT, int* __restrict__ idxout, float* __restrict__ vals)
{
    const int b = blockIdx.y, r = blockIdx.x;
    const int tid = threadIdx.x, w = tid >> 6, lane = tid & 63;

    const float* xr  = scr + OFF_XR;
    const float* yr  = scr + OFF_YR;
    const float* xg  = scr + OFF_XG;
    const float* G   = scr + OFF_G;
    const float* Gr  = scr + OFF_GR;
    const float* v2  = scr + OFF_V2;
    const float* c0p = scr + OFF_C0;
    const float* yT  = scr + OFF_YT;

    __shared__ float Gs[4][256];
    __shared__ float Grs[256];
    __shared__ float pdot[4][64];
    __shared__ float aux[12];       // [0..3]=H[t], [4..7]=ci partials
    __shared__ int gsh;
    __shared__ float Ys[49][260];

    // loads: G rows (coalesced), Gr row, H partials, ci partials
    *(float4*)&Gs[w][lane*4] =
        *(const float4*)(G + ((size_t)(b*256 + r*4 + w))*256 + lane*4);
    if (tid < 64)
        *(float4*)&Grs[tid*4] = *(const float4*)(Gr + ((size_t)(b*64 + r))*256 + tid*4);
    {
        const int pos = r*4 + w;
        float hacc = 0.f;
        #pragma unroll
        for (int j = 0; j < 4; j++) {
            const int c = lane + j*64;
            hacc += xg[((size_t)(b*256 + c))*256 + pos] * v2[c];
        }
        #pragma unroll
        for (int off = 32; off >= 1; off >>= 1) hacc += __shfl_xor(hacc, off);
        if (lane == 0) aux[w] = hacc + c0p[0];

        const int c = w*64 + lane;
        float cacc = xr[(size_t)(b*256 + c)*64 + r] * v2[c];
        #pragma unroll
        for (int off = 32; off >= 1; off >>= 1) cacc += __shfl_xor(cacc, off);
        if (lane == 0) aux[4 + w] = cacc;
    }
    __syncthreads();

    // a_r row: warp w covers c-chunk w
    {
        const float* yrB = yr + b*C*64;
        float d = 0.f;
        #pragma unroll 8
        for (int cc = 0; cc < 64; cc++) {
            const int c = w*64 + cc;
            d += Grs[c] * yrB[c*64 + lane];
        }
        pdot[w][lane] = d;
    }
    __syncthreads();

    // warp 0: full dot, arT write, top-4 (low-index tie-break)
    if (w == 0) {
        const float ci = aux[4] + aux[5] + aux[6] + aux[7] + c0p[0];
        const float dot = pdot[0][lane] + pdot[1][lane] + pdot[2][lane]
                        + pdot[3][lane] + ci;
        arT[(b*64 + lane)*64 + r] = dot * SCALE;
        float v = dot;
        const int my = lane;
        #pragma unroll
        for (int t = 0; t < NTOPK; t++) {
            float bv = v; int bi = my;
            #pragma unroll
            for (int off = 32; off >= 1; off >>= 1) {
                const float ov = __shfl_xor(bv, off);
                const int   oi = __shfl_xor(bi, off);
                if (ov > bv || (ov == bv && oi < bi)) { bv = ov; bi = oi; }
            }
            if (lane == 0) {
                idxout[(b*64 + r)*NTOPK + t] = bi;
                if (t == NTOPK-1) gsh = bi;
            }
            if (my == bi) v = -3.0e38f;
        }
    }
    __syncthreads();

    // stage yT rows for region g into LDS [k2][c] — coalesced float4
    const int g = gsh;
    const int gy = g >> 3, gx = g & 7;
    for (int i = tid; i < 49*64; i += 256) {
        const int k2 = i >> 6, f4 = i & 63;
        const int dy = d7(k2), dx = k2 - dy*7;
        const int kY = gy*7 + dy, kX = gx*7 + dx;
        float4 v = make_float4(0.f, 0.f, 0.f, 0.f);
        if (kY < HW && kX < HW)
            v = *(const float4*)(yT + ((size_t)(b*P + kY*HW + kX))*256 + f4*4);
        *(float4*)&Ys[k2][f4*4] = v;
    }
    __syncthreads();

    // vals[b,r,t,k2] = SCALE*(G_row . y_col + H)
    if (tid < NTOPK*49) {
        const int t = tid / 49, k2 = tid - (tid/49)*49;
        const int qX = (r & 7)*7 + t;
        const int dy = d7(k2), dx = k2 - dy*7;
        const int kY = gy*7 + dy, kX = gx*7 + dx;
        float res = 0.f;
        if (qX < HW && kY < HW && kX < HW) {
            const float4* Gp = (const float4*)&Gs[t][0];
            const float4* Yp = (const float4*)&Ys[k2][0];
            float dot = 0.f;
            #pragma unroll 8
            for (int cc = 0; cc < 64; cc++) {
                const float4 a = Gp[cc], yy = Yp[cc];
                dot += a.x*yy.x + a.y*yy.y + a.z*yy.z + a.w*yy.w;
            }
            res = SCALE * (dot + aux[t]);
        }
        vals[((b*64 + r)*NTOPK + t)*49 + k2] = res;
    }
}

// ============ K4: final fill — one block per (b, Y1, X1), nontemporal stores =
__global__ __launch_bounds__(256) void fill_kernel(
    const float* __restrict__ arT, const float* __restrict__ vals,
    const int* __restrict__ idx, float* __restrict__ out)
{
    const int b = blockIdx.y;
    const int yx = blockIdx.x;            // Y1*52 + X1
    const int Y1 = yx / HW, X1 = yx % HW;
    const int r1 = (Y1/7)*8 + X1/7;
    const int q1 = (Y1%7)*7 + X1%7;
    const int p2 = r1*49 + q1;
    const int yy = p2/56, xx = p2 - 56*yy;
    const int regB = (yy/7)*8 + xx/7;

    __shared__ float acol[64];
    __shared__ float vrow[49];
    const int tid = threadIdx.x;
    if (tid < 64) acol[tid] = arT[(b*64 + regB)*64 + tid];
    int ovr = -1;
    if (q1 < NTOPK) {
        ovr = idx[(b*64 + r1)*NTOPK + q1];
        if (tid < 49) vrow[tid] = vals[((b*64 + r1)*NTOPK + q1)*49 + tid];
    }
    __syncthreads();

    float* plane = out + (size_t)(b*P + yx) * P;
    for (int u = tid; u < 676; u += 256) {       // 676 = 52*13 float4 groups
        const int Y2 = d13(u);
        const int g4 = u - Y2*13;
        const int X2b = g4*4;
        const int ry2 = d7(Y2);
        const int my2 = Y2 - ry2*7;
        float res[4];
        #pragma unroll
        for (int j = 0; j < 4; j++) {
            const int X2 = X2b + j;
            const int rx2 = d7(X2);
            const int mx2 = X2 - rx2*7;
            const int r2 = ry2*8 + rx2;
            const int k2 = my2*7 + mx2;
            const int P1 = r2*49 + k2;
            const int Yp = d56(P1);
            const int Xp = P1 - Yp*56;
            const int regA = d7(Yp)*8 + d7(Xp);
            float v = acol[regA];
            if (r2 == ovr) v = vrow[k2];
            res[j] = v;
        }
        nt_f32x4 o;
        o.x = res[0]; o.y = res[1]; o.z = res[2]; o.w = res[3];
        __builtin_nontemporal_store(o, (nt_f32x4*)(plane + Y2*HW + X2b));
    }
}

extern "C" void kernel_launch(void* const* d_in, const int* in_sizes, int n_in,
                              void* d_out, int out_size, void* d_ws, size_t ws_size,
                              hipStream_t stream)
{
    const float* x  = (const float*)d_in[0];
    const float* y  = (const float*)d_in[1];
    const float* qw = (const float*)d_in[2];
    const float* qb = (const float*)d_in[3];
    const float* kw = (const float*)d_in[4];
    const float* kb = (const float*)d_in[5];
    float* out = (float*)d_out;

    // Large scratch at front of d_out (~28.2 MB << 234 MB out buffer);
    // fully consumed by k3 before fill_kernel overwrites d_out.
    float* scr = out;

    // fill-consumed small arrays stay in d_ws
    float* ws  = (float*)d_ws;
    float* arT = ws;                          // 8*64*64 = 32768
    float* vls = arT + 32768;                 // 8*64*4*49 = 100352
    int*   idx = (int*)(vls + 100352);        // 8*64*4 ints

    k1_pool_prep_tr<<<2465, 256, 0, stream>>>(x, y, qw, qb, kw, kb, scr);
    k2_gemms<<<160, 256, 0, stream>>>(scr);
    k3_topk_vals<<<dim3(64, 8), 256, 0, stream>>>(scr, arT, idx, vls);
    fill_kernel<<<dim3(P, 8), 256, 0, stream>>>(arT, vls, idx, out);
}